// Round 5
// baseline (419.441 us; speedup 1.0000x reference)
//
#include <hip/hip_runtime.h>

#define N_NODES 50000
#define D 128
#define R 8
#define E_EDGES 600000
#define NR (N_NODES * R)                 // 400000 (rel,dst) keys: key = r*N + dst
#define SCAN_BLOCKS ((NR + 1023) / 1024) // 391

typedef unsigned short ushort_t;
typedef unsigned int uint_t;
typedef __attribute__((ext_vector_type(8))) short short8;
typedef __attribute__((ext_vector_type(8))) ushort_t ushort8;
typedef __attribute__((ext_vector_type(4))) float f32x4;

// ws layout: [0,NR) int counts->offsets->ends ; [NR,NR+E) int bucket ;
// then WtH (9*128*128 ushort), WtL (same). Total ~4.6 MB.

static __device__ __forceinline__ ushort_t f2bf(float f) {
    uint_t u = __float_as_uint(f);
    uint_t r = u + 0x7fffu + ((u >> 16) & 1u);
    return (ushort_t)(r >> 16);
}
static __device__ __forceinline__ float bf2f(ushort_t h) {
    return __uint_as_float(((uint_t)h) << 16);
}

__global__ void __launch_bounds__(256)
count_kernel(const int* __restrict__ ei, const int* __restrict__ et,
             int* __restrict__ cnt) {
    int e = blockIdx.x * 256 + threadIdx.x;
    if (e < E_EDGES) {
        int dst = ei[E_EDGES + e];
        int r = et[e];
        atomicAdd(&cnt[r * N_NODES + dst], 1);
    }
}

__global__ void __launch_bounds__(256)
scan1_kernel(int* __restrict__ off, int* __restrict__ part) {
    __shared__ int wsum[4];
    int tid = threadIdx.x, lane = tid & 63, wid = tid >> 6;
    int base = blockIdx.x * 1024 + tid * 4;
    int c0 = 0, c1 = 0, c2 = 0, c3 = 0;
    if (base + 0 < NR) c0 = off[base + 0];
    if (base + 1 < NR) c1 = off[base + 1];
    if (base + 2 < NR) c2 = off[base + 2];
    if (base + 3 < NR) c3 = off[base + 3];
    int ts = c0 + c1 + c2 + c3;
    int v = ts;
#pragma unroll
    for (int o = 1; o < 64; o <<= 1) {
        int u = __shfl_up(v, o, 64);
        if (lane >= o) v += u;
    }
    if (lane == 63) wsum[wid] = v;
    __syncthreads();
    int wbase = 0;
#pragma unroll
    for (int w = 0; w < 4; ++w)
        if (w < wid) wbase += wsum[w];
    int excl = wbase + v - ts;
    if (base + 0 < NR) off[base + 0] = excl;
    if (base + 1 < NR) off[base + 1] = excl + c0;
    if (base + 2 < NR) off[base + 2] = excl + c0 + c1;
    if (base + 3 < NR) off[base + 3] = excl + c0 + c1 + c2;
    if (tid == 0) part[blockIdx.x] = wsum[0] + wsum[1] + wsum[2] + wsum[3];
}

__global__ void __launch_bounds__(512)
scan2_kernel(int* __restrict__ part) {
    __shared__ int sp[SCAN_BLOCKS];
    int tid = threadIdx.x;
    if (tid < SCAN_BLOCKS) sp[tid] = part[tid];
    __syncthreads();
    if (tid == 0) {
        int acc = 0;
        for (int i = 0; i < SCAN_BLOCKS; ++i) { int t = sp[i]; sp[i] = acc; acc += t; }
    }
    __syncthreads();
    if (tid < SCAN_BLOCKS) part[tid] = sp[tid];
}

__global__ void __launch_bounds__(256)
scan3_kernel(int* __restrict__ off, const int* __restrict__ part) {
    int p = part[blockIdx.x];
    int base = blockIdx.x * 1024 + threadIdx.x * 4;
#pragma unroll
    for (int i = 0; i < 4; ++i)
        if (base + i < NR) off[base + i] += p;
}

__global__ void __launch_bounds__(256)
bucket_kernel(const int* __restrict__ ei, const int* __restrict__ et,
              int* __restrict__ off, int* __restrict__ bucket) {
    int e = blockIdx.x * 256 + threadIdx.x;
    if (e < E_EDGES) {
        int src = ei[e];
        int dst = ei[E_EDGES + e];
        int r = et[e];
        int key = r * N_NODES + dst;
        int pos = atomicAdd(&off[key], 1);
        bucket[pos] = src;
    }
}

// One-time: W[r][k][col] fp32 -> Wt[r][col][k] bf16 hi/lo (B-fragment-friendly).
__global__ void __launch_bounds__(256)
wt_kernel(const float* __restrict__ W, const float* __restrict__ Wroot,
          ushort_t* __restrict__ WtH, ushort_t* __restrict__ WtL) {
    int r = blockIdx.x;
    const float* Wr = (r < 8) ? (W + ((size_t)r << 14)) : Wroot;
    __shared__ float T[32][129];
    int tid = threadIdx.x;
    for (int k0 = 0; k0 < D; k0 += 32) {
#pragma unroll
        for (int u = 0; u < 16; ++u) {
            int idx = tid + u * 256;
            T[idx >> 7][idx & 127] = Wr[(size_t)k0 * D + idx];
        }
        __syncthreads();
        int col = tid & 127, kh = tid >> 7;
        ushort8 h0, h1, l0, l1;
#pragma unroll
        for (int kk = 0; kk < 8; ++kk) {
            float f = T[kh * 16 + kk][col];
            ushort_t hb = f2bf(f);
            h0[kk] = hb; l0[kk] = f2bf(f - bf2f(hb));
        }
#pragma unroll
        for (int kk = 0; kk < 8; ++kk) {
            float f = T[kh * 16 + 8 + kk][col];
            ushort_t hb = f2bf(f);
            h1[kk] = hb; l1[kk] = f2bf(f - bf2f(hb));
        }
        size_t o = ((size_t)r << 14) + (size_t)col * D + k0 + kh * 16;
        *(ushort8*)&WtH[o] = h0; *(ushort8*)&WtH[o + 8] = h1;
        *(ushort8*)&WtL[o] = l0; *(ushort8*)&WtL[o + 8] = l1;
        __syncthreads();
    }
}

// One block = 64 dsts. Per r in 0..8: gather per-(dst,r) mean (r=8: x[dst]) into
// At bf16 hi/lo [dst][k] with XOR-16 slot swizzle; MFMA 16x16x32 bf16, 3-product
// hi/lo split, acc carried across all 9 relations; epilogue bias+ReLU.
__global__ void __launch_bounds__(256, 4)
fused_kernel(const float* __restrict__ x,
             const ushort_t* __restrict__ WtH, const ushort_t* __restrict__ WtL,
             const float* __restrict__ bias, const int* __restrict__ ends,
             const int* __restrict__ bucket, float* __restrict__ out) {
    __shared__ ushort_t At_hi[64 * 128];  // 16 KB, [dst][k] + slot swizzle
    __shared__ ushort_t At_lo[64 * 128];  // 16 KB
    __shared__ float bs[128];

    int tid = threadIdx.x;
    if (tid < 128) bs[tid] = bias[tid];
    int lane = tid & 63;
    int wave = tid >> 6;       // gather: col-quarter; GEMM: row-block
    int mrow = lane & 15;      // MFMA: A-row / B-col within tile
    int kg = lane >> 4;        // MFMA: k-group (8 consecutive k)
    int n0 = blockIdx.x * 64;
    int n = n0 + lane;         // gather dst (lane == dst slot)

    f32x4 acc[8];
#pragma unroll
    for (int t = 0; t < 8; ++t) acc[t] = (f32x4){0.f, 0.f, 0.f, 0.f};

    for (int r = 0; r < 9; ++r) {
        // segment bounds once per relation
        int s = 0, epos = 0;
        float inv = 0.0f;
        if (r < 8 && n < N_NODES) {
            int key = r * N_NODES + n;
            s = (key == 0) ? 0 : ends[key - 1];
            epos = ends[key];
            inv = (epos > s) ? 1.0f / (float)(epos - s) : 0.0f;
        }
        __syncthreads();  // previous relation's MFMA done reading At
#pragma unroll
        for (int pass = 0; pass < 2; ++pass) {
            int cbase = (wave << 5) + pass * 16;
            float ga[16];
#pragma unroll
            for (int c = 0; c < 16; ++c) ga[c] = 0.0f;
            if (r < 8) {
                for (int p = s; p < epos; ++p) {
                    int src = bucket[p];
                    const float4* xp = (const float4*)(x + (size_t)src * D + cbase);
#pragma unroll
                    for (int u = 0; u < 4; ++u) {
                        float4 v = xp[u];
                        ga[u * 4 + 0] += v.x; ga[u * 4 + 1] += v.y;
                        ga[u * 4 + 2] += v.z; ga[u * 4 + 3] += v.w;
                    }
                }
#pragma unroll
                for (int c = 0; c < 16; ++c) ga[c] *= inv;
            } else if (n < N_NODES) {
                const float4* xp = (const float4*)(x + (size_t)n * D + cbase);
#pragma unroll
                for (int u = 0; u < 4; ++u) {
                    float4 v = xp[u];
                    ga[u * 4 + 0] = v.x; ga[u * 4 + 1] = v.y;
                    ga[u * 4 + 2] = v.z; ga[u * 4 + 3] = v.w;
                }
            }
            // convert + swizzled LDS write (two 8-k chunks of 16B)
#pragma unroll
            for (int chunk = 0; chunk < 2; ++chunk) {
                ushort8 h, l;
#pragma unroll
                for (int j = 0; j < 8; ++j) {
                    float f = ga[chunk * 8 + j];
                    ushort_t hb = f2bf(f);
                    h[j] = hb;
                    l[j] = f2bf(f - bf2f(hb));
                }
                int k = cbase + chunk * 8;
                int slot = k >> 3;                       // 16B slot 0..15
                int idx = lane * 128 + ((slot ^ (lane & 15)) << 3);
                *(ushort8*)&At_hi[idx] = h;
                *(ushort8*)&At_lo[idx] = l;
            }
        }
        __syncthreads();

        // MFMA: wave handles dst rows wave*16..+15, all 128 cols (8 tiles)
        const ushort_t* WH = WtH + ((size_t)r << 14);
        const ushort_t* WL = WtL + ((size_t)r << 14);
#pragma unroll
        for (int kstep = 0; kstep < 4; ++kstep) {
            int arow = wave * 16 + mrow;
            int slotA = kstep * 4 + kg;
            int aidx = arow * 128 + ((slotA ^ mrow) << 3);
            short8 ah = *(const short8*)&At_hi[aidx];
            short8 al = *(const short8*)&At_lo[aidx];
            int kofs = kstep * 32 + kg * 8;
#pragma unroll
            for (int nt = 0; nt < 8; ++nt) {
                int col = nt * 16 + mrow;
                short8 bh = *(const short8*)&WH[(size_t)col * D + kofs];
                short8 bl = *(const short8*)&WL[(size_t)col * D + kofs];
                acc[nt] = __builtin_amdgcn_mfma_f32_16x16x32_bf16(ah, bh, acc[nt], 0, 0, 0);
                acc[nt] = __builtin_amdgcn_mfma_f32_16x16x32_bf16(ah, bl, acc[nt], 0, 0, 0);
                acc[nt] = __builtin_amdgcn_mfma_f32_16x16x32_bf16(al, bh, acc[nt], 0, 0, 0);
            }
        }
    }

    // epilogue: D layout col=lane&15, row=(lane>>4)*4+j
#pragma unroll
    for (int nt = 0; nt < 8; ++nt) {
        int col = nt * 16 + mrow;
        float bb = bs[col];
#pragma unroll
        for (int j = 0; j < 4; ++j) {
            int nn = n0 + wave * 16 + kg * 4 + j;
            if (nn < N_NODES) {
                float v = acc[nt][j] + bb;
                out[(size_t)nn * D + col] = v > 0.f ? v : 0.f;
            }
        }
    }
}

extern "C" void kernel_launch(void* const* d_in, const int* in_sizes, int n_in,
                              void* d_out, int out_size, void* d_ws, size_t ws_size,
                              hipStream_t stream) {
    const float* x     = (const float*)d_in[0];
    const int*   ei    = (const int*)d_in[1];
    const int*   et    = (const int*)d_in[2];
    const float* W     = (const float*)d_in[3];
    const float* Wroot = (const float*)d_in[4];
    const float* b     = (const float*)d_in[5];
    float* out = (float*)d_out;
    int* ws = (int*)d_ws;
    int* off = ws;                                   // NR ints
    int* bucket = ws + NR;                           // E ints
    ushort_t* WtH = (ushort_t*)(ws + NR + E_EDGES);  // 9*16384 ushorts
    ushort_t* WtL = WtH + 9 * 16384;

    hipMemsetAsync(d_ws, 0, (size_t)NR * sizeof(int), stream);

    count_kernel<<<(E_EDGES + 255) / 256, 256, 0, stream>>>(ei, et, off);
    wt_kernel<<<9, 256, 0, stream>>>(W, Wroot, WtH, WtL);
    scan1_kernel<<<SCAN_BLOCKS, 256, 0, stream>>>(off, bucket);
    scan2_kernel<<<1, 512, 0, stream>>>(bucket);
    scan3_kernel<<<SCAN_BLOCKS, 256, 0, stream>>>(off, bucket);
    bucket_kernel<<<(E_EDGES + 255) / 256, 256, 0, stream>>>(ei, et, off, bucket);
    fused_kernel<<<(N_NODES + 63) / 64, 256, 0, stream>>>(x, WtH, WtL, b, off,
                                                          bucket, out);
}